// Round 7
// baseline (639.887 us; speedup 1.0000x reference)
//
#include <hip/hip_runtime.h>
#include <math.h>

// Problem constants
#define H_   768
#define NH_  12
#define DH_  64
#define NL_  50
#define NC_  16
#define S_   8192
#define NLH_ 640     // padded (h,l) columns (600 used)
#define MT_  64      // m-tiles of 128 s-rows
#define NT3_ 10      // n-tiles of 64 cols

typedef __attribute__((ext_vector_type(8))) short short8;
typedef __attribute__((ext_vector_type(4))) float f32x4;
typedef unsigned short u16;

#define AS1(p) ((const __attribute__((address_space(1))) void*)(p))
#define AS3(p) ((__attribute__((address_space(3))) void*)(p))

__device__ inline u16 f2b(float f) {
    union { float f; unsigned u; } x; x.f = f;
    return (u16)((x.u + 0x7FFFu + ((x.u >> 16) & 1u)) >> 16);
}

// ---------------------------------------------------------------------------
// prep1: blocks 0..47: small fp32 GEMMs  q = 0.125*(lq@wq^T + bq),  M2 = lw@ow
//        blocks 48..3119: enc fp32 -> bf16 (linear)
// ---------------------------------------------------------------------------
__global__ __launch_bounds__(256)
void prep1(const float* __restrict__ enc, const float* __restrict__ lq,
           const float* __restrict__ lwt, const float* __restrict__ ipw,
           const float* __restrict__ ipb, const float* __restrict__ ow,
           u16* __restrict__ enc_b, float* __restrict__ qf, float* __restrict__ M2)
{
    const int b = blockIdx.x, t = threadIdx.x;
    if (b < 48) {
        const int mat = b / 24, jg = b % 24;
        const int tx = t & 31, ty = t >> 5;      // 32 cols x 8 row-groups(7)
        const int col = jg * 32 + tx;
        const int l0 = ty * 7;
        float acc[7];
        #pragma unroll
        for (int r = 0; r < 7; ++r) acc[r] = 0.f;
        if (mat == 0) {
            const float* B = ipw + (long)col * H_;        // wq row `col`
            for (int k = 0; k < H_; ++k) {
                const float bv = B[k];
                #pragma unroll
                for (int r = 0; r < 7; ++r)
                    if (l0 + r < NL_) acc[r] += lq[(long)(l0 + r) * H_ + k] * bv;
            }
            #pragma unroll
            for (int r = 0; r < 7; ++r)
                if (l0 + r < NL_)
                    qf[(long)(l0 + r) * H_ + col] = 0.125f * (acc[r] + ipb[col]);
        } else {
            for (int k = 0; k < H_; ++k) {
                const float bv = ow[(long)k * H_ + col];  // M2[l,col]=sum_k lw[l,k]ow[k,col]
                #pragma unroll
                for (int r = 0; r < 7; ++r)
                    if (l0 + r < NL_) acc[r] += lwt[(long)(l0 + r) * H_ + k] * bv;
            }
            #pragma unroll
            for (int r = 0; r < 7; ++r)
                if (l0 + r < NL_) M2[(long)(l0 + r) * H_ + col] = acc[r];
        }
        return;
    }
    const long i8 = (long)(b - 48) * 2048 + (long)t * 8;
    const float4 v0 = *reinterpret_cast<const float4*>(enc + i8);
    const float4 v1 = *reinterpret_cast<const float4*>(enc + i8 + 4);
    short8 o;
    o[0] = f2b(v0.x); o[1] = f2b(v0.y); o[2] = f2b(v0.z); o[3] = f2b(v0.w);
    o[4] = f2b(v1.x); o[5] = f2b(v1.y); o[6] = f2b(v1.z); o[7] = f2b(v1.w);
    *reinterpret_cast<short8*>(enc_b + i8) = o;
}

// ---------------------------------------------------------------------------
// prep2: blocks 0..287: qk[(h*50+l), j] = sum_d qf[l,h64+d]*wk[h64+d, j]
//                       W2[(h*50+l), j] = sum_d M2[l,h64+d]*wv[h64+d, j]
//        (bk dropped: per-column constant cancels in softmax over s)
//        block 288: zero pad rows 600..639 of both
//        block 289: constL[l] = sum_i M2[l,i]*bv[i] + lw[l,i]*ob[i]
// ---------------------------------------------------------------------------
__global__ __launch_bounds__(256)
void prep2(const float* __restrict__ qf, const float* __restrict__ M2,
           const float* __restrict__ ipw, const float* __restrict__ ipb,
           const float* __restrict__ lwt, const float* __restrict__ ob,
           u16* __restrict__ qkL, u16* __restrict__ W2L, float* __restrict__ constL)
{
    const int b = blockIdx.x, t = threadIdx.x;
    if (b < 288) {
        const int mat = b / 144, r2 = b % 144, h = r2 / 12, jg = r2 % 12;
        const int tx = t & 63, ty = t >> 6;      // 64 cols x 4 row-groups(13)
        const int j = jg * 64 + tx;
        const int l0 = ty * 13;
        const float* A = (mat == 0 ? qf : M2);
        const float* B = ipw + ((long)(H_ + mat * H_ + h * DH_)) * H_ + j;
        u16* O = (mat == 0 ? qkL : W2L);
        float acc[13];
        #pragma unroll
        for (int r = 0; r < 13; ++r) acc[r] = 0.f;
        for (int d = 0; d < DH_; ++d) {
            const float bv = B[(long)d * H_];
            #pragma unroll
            for (int r = 0; r < 13; ++r)
                if (l0 + r < NL_) acc[r] += A[(long)(l0 + r) * H_ + h * DH_ + d] * bv;
        }
        #pragma unroll
        for (int r = 0; r < 13; ++r)
            if (l0 + r < NL_)
                O[(long)(h * NL_ + l0 + r) * H_ + j] = f2b(acc[r]);
        return;
    }
    if (b == 288) {
        for (int i = t; i < 40 * H_; i += 256) {
            qkL[(long)600 * H_ + i] = 0;
            W2L[(long)600 * H_ + i] = 0;
        }
        return;
    }
    // b == 289: constL
    __shared__ float r4[4];
    const int lane = t & 63, w = t >> 6;
    for (int l = 0; l < NL_; ++l) {
        float s = 0.f;
        for (int i = t; i < H_; i += 256)
            s += M2[(long)l * H_ + i] * ipb[2 * H_ + i] + lwt[(long)l * H_ + i] * ob[i];
        #pragma unroll
        for (int o2 = 1; o2 < 64; o2 <<= 1) s += __shfl_xor(s, o2);
        if (lane == 0) r4[w] = s;
        __syncthreads();
        if (t == 0) constL[l] = r4[0] + r4[1] + r4[2] + r4[3];
        __syncthreads();
    }
}

// ---------------------------------------------------------------------------
// fused_gemm: block = (128 s-rows) x (64 lh-cols), computes BOTH
//   logits = enc @ qk^T  and  Z = enc @ W2^T  for the tile, then the
//   softmax PARTIALS over its 128 rows in the epilogue:
//   pm[mt,lh] = max_s logit ; pp = sum e^{x-pm} ; pZ = sum e^{x-pm} * Z.
// K-loop: R5-proven 3-buffer rotation + counted vmcnt(4) + raw s_barrier.
// XOR slot swizzle (0 bank conflicts), XCD-bijective remap (640 = 8*80).
// ---------------------------------------------------------------------------
__global__ __launch_bounds__(256)
void fused_gemm(const u16* __restrict__ enc_b, const u16* __restrict__ qkL,
                const u16* __restrict__ W2L,
                float* __restrict__ pmg, float* __restrict__ ppg,
                float* __restrict__ pzg)
{
    const int flat = blockIdx.y * NT3_ + blockIdx.x;       // 0..639
    const int rem  = (flat & 7) * 80 + (flat >> 3);        // XCD-bijective
    const int mt   = rem / NT3_, ntb = rem % NT3_;
    const long m0 = (long)mt * 128, n0 = (long)ntb * 64;

    __shared__ u16 As[3][4096];      // 128 x 32
    __shared__ u16 Bqs[3][2048];     // 64 x 32
    __shared__ u16 Bzs[3][2048];
    __shared__ float redm[128], redsum[128], redz[128];

    const int tid = threadIdx.x, lane = tid & 63, w = tid >> 6;
    const int wr = w >> 1, wc = w & 1;
    const int sr0 = tid >> 2, sp = tid & 3;

    f32x4 accq[4][2], accz[4][2];
    #pragma unroll
    for (int m = 0; m < 4; ++m)
        #pragma unroll
        for (int n = 0; n < 2; ++n)
            #pragma unroll
            for (int j = 0; j < 4; ++j) { accq[m][n][j] = 0.f; accz[m][n][j] = 0.f; }

    auto stage = [&](int t, int buf) {
        const int k0 = t * 32;
        #pragma unroll
        for (int tt = 0; tt < 2; ++tt) {
            const int row = tt * 64 + sr0;
            const int ss  = sp ^ ((row >> 1) & 3);
            __builtin_amdgcn_global_load_lds(AS1(enc_b + (m0 + row) * H_ + k0 + ss * 8),
                                             AS3(As[buf] + (tt * 256 + tid) * 8), 16, 0, 0);
        }
        const int ss0 = sp ^ ((sr0 >> 1) & 3);
        __builtin_amdgcn_global_load_lds(AS1(qkL + (n0 + sr0) * H_ + k0 + ss0 * 8),
                                         AS3(Bqs[buf] + tid * 8), 16, 0, 0);
        __builtin_amdgcn_global_load_lds(AS1(W2L + (n0 + sr0) * H_ + k0 + ss0 * 8),
                                         AS3(Bzs[buf] + tid * 8), 16, 0, 0);
    };

    stage(0, 0);
    stage(1, 1);

    const int rr = lane & 15, g = lane >> 4;
    const int ro = (g ^ ((rr >> 1) & 3)) * 8;

    for (int t = 0; t < 24; ++t) {
        if (t < 23) asm volatile("s_waitcnt vmcnt(4)" ::: "memory");
        else        asm volatile("s_waitcnt vmcnt(0)" ::: "memory");
        __builtin_amdgcn_s_barrier();
        __builtin_amdgcn_sched_barrier(0);

        const int cb = t % 3;
        short8 a[4], bq[2], bz[2];
        #pragma unroll
        for (int m = 0; m < 4; ++m)
            a[m] = *reinterpret_cast<const short8*>(As[cb] + (wr * 64 + m * 16 + rr) * 32 + ro);
        #pragma unroll
        for (int n = 0; n < 2; ++n) {
            bq[n] = *reinterpret_cast<const short8*>(Bqs[cb] + (wc * 32 + n * 16 + rr) * 32 + ro);
            bz[n] = *reinterpret_cast<const short8*>(Bzs[cb] + (wc * 32 + n * 16 + rr) * 32 + ro);
        }
        #pragma unroll
        for (int m = 0; m < 4; ++m)
            #pragma unroll
            for (int n = 0; n < 2; ++n) {
                accq[m][n] = __builtin_amdgcn_mfma_f32_16x16x32_bf16(a[m], bq[n], accq[m][n], 0, 0, 0);
                accz[m][n] = __builtin_amdgcn_mfma_f32_16x16x32_bf16(a[m], bz[n], accz[m][n], 0, 0, 0);
            }

        if (t + 2 < 24) stage(t + 2, (t + 2) % 3);
    }

    // ---- epilogue: softmax partials over this block's 128 rows ----
    // acc element (m,n,j): row = wr*64 + m*16 + g*4 + j, col = wc*32 + n*16 + rr
    #pragma unroll
    for (int n = 0; n < 2; ++n) {
        float m_ = -INFINITY;
        #pragma unroll
        for (int mm = 0; mm < 4; ++mm)
            #pragma unroll
            for (int j = 0; j < 4; ++j) m_ = fmaxf(m_, accq[mm][n][j]);
        m_ = fmaxf(m_, __shfl_xor(m_, 16));
        m_ = fmaxf(m_, __shfl_xor(m_, 32));
        if (g == 0) redm[wr * 64 + wc * 32 + n * 16 + rr] = m_;
    }
    __syncthreads();
    #pragma unroll
    for (int n = 0; n < 2; ++n) {
        const int col = wc * 32 + n * 16 + rr;
        const float gm = fmaxf(redm[col], redm[64 + col]);
        float s_ = 0.f, z_ = 0.f;
        #pragma unroll
        for (int mm = 0; mm < 4; ++mm)
            #pragma unroll
            for (int j = 0; j < 4; ++j) {
                const float e = __expf(accq[mm][n][j] - gm);
                s_ += e;
                z_ += e * accz[mm][n][j];
            }
        s_ += __shfl_xor(s_, 16); s_ += __shfl_xor(s_, 32);
        z_ += __shfl_xor(z_, 16); z_ += __shfl_xor(z_, 32);
        if (g == 0) { redsum[wr * 64 + col] = s_; redz[wr * 64 + col] = z_; }
    }
    __syncthreads();
    if (tid < 64) {
        const int col = tid;
        const long o = (long)mt * NLH_ + n0 + col;
        pmg[o] = fmaxf(redm[col], redm[64 + col]);
        ppg[o] = redsum[col] + redsum[64 + col];
        pzg[o] = redz[col] + redz[64 + col];
    }
}

// ---------------------------------------------------------------------------
// combine: block = label l, 64 threads. Thread h (<12) runs the 64-step
// scalar flash-prefix over m-tiles; emits at every 4th tile (512-row chunk).
// score[c,l] = sum_h A/S + constL[l].
// ---------------------------------------------------------------------------
__global__ __launch_bounds__(64)
void combine(const float* __restrict__ pmg, const float* __restrict__ ppg,
             const float* __restrict__ pzg, const float* __restrict__ constL,
             float* __restrict__ out)
{
    const int l = blockIdx.x, t = threadIdx.x;
    __shared__ float sc[16][12];
    if (t < NH_) {
        const int lh = t * NL_ + l;
        float M = -INFINITY, S = 0.f, A = 0.f;
        for (int mt = 0; mt < MT_; ++mt) {
            const long o = (long)mt * NLH_ + lh;
            const float mc = pmg[o], pc = ppg[o], zc = pzg[o];
            const float Mn = fmaxf(M, mc);
            const float ea = __expf(M - Mn), eb = __expf(mc - Mn);
            S = S * ea + pc * eb;
            A = A * ea + zc * eb;
            M = Mn;
            if ((mt & 3) == 3) sc[mt >> 2][t] = A / S;
        }
    }
    __syncthreads();
    if (t < NC_) {
        float s = constL[l];
        #pragma unroll
        for (int h = 0; h < NH_; ++h) s += sc[t][h];
        out[(long)t * NL_ + l] = s;
    }
}

// ---------------------------------------------------------------------------
extern "C" void kernel_launch(void* const* d_in, const int* in_sizes, int n_in,
                              void* d_out, int out_size, void* d_ws, size_t ws_size,
                              hipStream_t stream) {
    const float* enc = (const float*)d_in[0];
    const float* lq  = (const float*)d_in[1];
    const float* lwt = (const float*)d_in[2];   // flat == lw (50, 768)
    const float* ipw = (const float*)d_in[3];
    const float* ipb = (const float*)d_in[4];
    const float* ow  = (const float*)d_in[5];
    const float* ob  = (const float*)d_in[6];
    float* out = (float*)d_out;

    // workspace
    float* wsf    = (float*)d_ws;
    float* qf     = wsf;                         // 50*768
    float* M2     = qf + (long)NL_ * H_;         // 50*768
    float* constL = M2 + (long)NL_ * H_;         // 64
    float* pmg    = constL + 64;                 // 64*640
    float* ppg    = pmg + (long)MT_ * NLH_;
    float* pzg    = ppg + (long)MT_ * NLH_;
    u16* enc_b = (u16*)(pzg + (long)MT_ * NLH_); // 8192*768
    u16* qkL   = enc_b + (long)S_ * H_;          // 640*768
    u16* W2L   = qkL + (long)NLH_ * H_;          // 640*768

    prep1<<<dim3(48 + 3072), 256, 0, stream>>>(enc, lq, lwt, ipw, ipb, ow,
                                               enc_b, qf, M2);

    prep2<<<dim3(290), 256, 0, stream>>>(qf, M2, ipw, ipb, lwt, ob,
                                         qkL, W2L, constL);

    fused_gemm<<<dim3(NT3_, MT_), 256, 0, stream>>>(enc_b, qkL, W2L, pmg, ppg, pzg);

    combine<<<dim3(NL_), 64, 0, stream>>>(pmg, ppg, pzg, constL, out);
}

// Round 8
// 186.181 us; speedup vs baseline: 3.4369x; 3.4369x over previous
//
#include <hip/hip_runtime.h>
#include <math.h>

// Problem constants
#define H_   768
#define NH_  12
#define DH_  64
#define NL_  50
#define NC_  16
#define S_   8192
#define NLH_ 640     // padded (h,l) columns (600 used)
#define MT_  64      // m-tiles of 128 s-rows
#define NT3_ 10      // n-tiles of 64 cols

typedef __attribute__((ext_vector_type(8))) short short8;
typedef __attribute__((ext_vector_type(4))) float f32x4;
typedef unsigned short u16;

#define AS1(p) ((const __attribute__((address_space(1))) void*)(p))
#define AS3(p) ((__attribute__((address_space(3))) void*)(p))

__device__ inline u16 f2b(float f) {
    union { float f; unsigned u; } x; x.f = f;
    return (u16)((x.u + 0x7FFFu + ((x.u >> 16) & 1u)) >> 16);
}

// ---------------------------------------------------------------------------
// prep1 (one launch, block ranges):
//   blocks 0..3071        : enc fp32 -> bf16 (linear, BW-bound)
//   blocks 3072..3083 (12): qf = 0.125*(lq @ wq^T + bq)  -- tiled-LDS fp32 GEMM
//   blocks 3084..3239(156): M2 = lw @ ow                 -- coalesced k-loop
// ---------------------------------------------------------------------------
#define PB_CONV 3072
#define PB_QF   12
#define PB_M2   156

__global__ __launch_bounds__(256)
void prep1(const float* __restrict__ enc, const float* __restrict__ lq,
           const float* __restrict__ lwt, const float* __restrict__ ipw,
           const float* __restrict__ ipb, const float* __restrict__ ow,
           u16* __restrict__ enc_b, float* __restrict__ qf, float* __restrict__ M2)
{
    __shared__ float As[16][128];   // 8 KB (qf-GEMM only)
    __shared__ float Bs[16][64];    // 4 KB

    const int b = blockIdx.x, tid = threadIdx.x;

    if (b < PB_CONV) {
        const long i8 = (long)b * 2048 + (long)tid * 8;
        const float4 v0 = *reinterpret_cast<const float4*>(enc + i8);
        const float4 v1 = *reinterpret_cast<const float4*>(enc + i8 + 4);
        short8 o;
        o[0] = f2b(v0.x); o[1] = f2b(v0.y); o[2] = f2b(v0.z); o[3] = f2b(v0.w);
        o[4] = f2b(v1.x); o[5] = f2b(v1.y); o[6] = f2b(v1.z); o[7] = f2b(v1.w);
        *reinterpret_cast<short8*>(enc_b + i8) = o;
        return;
    }

    if (b < PB_CONV + PB_QF) {
        // ---- qf tile: BM=128 (M=50), BN=64, BK=16, TM=8, TN=4 ----
        const long n0 = (long)(b - PB_CONV) * 64;
        const int tx = tid & 15, ty = tid >> 4;
        float acc[2][4][4];
        #pragma unroll
        for (int a = 0; a < 2; ++a)
            #pragma unroll
            for (int i = 0; i < 4; ++i)
                #pragma unroll
                for (int j = 0; j < 4; ++j) acc[a][i][j] = 0.f;

        for (int k0 = 0; k0 < H_; k0 += 16) {
            #pragma unroll
            for (int s = tid; s < 512; s += 256) {
                const int row = s >> 2, kq = s & 3;
                float4 val = make_float4(0.f, 0.f, 0.f, 0.f);
                if (row < NL_)
                    val = *reinterpret_cast<const float4*>(lq + (long)row * H_ + k0 + kq * 4);
                As[kq * 4 + 0][row] = val.x;
                As[kq * 4 + 1][row] = val.y;
                As[kq * 4 + 2][row] = val.z;
                As[kq * 4 + 3][row] = val.w;
            }
            {
                const int s = tid;  // 256 granules: 64 rows x 4 kq
                const int row = s >> 2, kq = s & 3;
                const float4 val = *reinterpret_cast<const float4*>(
                    ipw + (n0 + row) * H_ + k0 + kq * 4);   // wq rows
                Bs[kq * 4 + 0][row] = val.x;
                Bs[kq * 4 + 1][row] = val.y;
                Bs[kq * 4 + 2][row] = val.z;
                Bs[kq * 4 + 3][row] = val.w;
            }
            __syncthreads();
            #pragma unroll
            for (int kk = 0; kk < 16; ++kk) {
                float av[2][4], bv[4];
                #pragma unroll
                for (int g2 = 0; g2 < 2; ++g2)
                    *reinterpret_cast<float4*>(av[g2]) =
                        *reinterpret_cast<const float4*>(&As[kk][g2 * 64 + ty * 4]);
                *reinterpret_cast<float4*>(bv) =
                    *reinterpret_cast<const float4*>(&Bs[kk][tx * 4]);
                #pragma unroll
                for (int a = 0; a < 2; ++a)
                    #pragma unroll
                    for (int i = 0; i < 4; ++i)
                        #pragma unroll
                        for (int j = 0; j < 4; ++j)
                            acc[a][i][j] += av[a][i] * bv[j];
            }
            __syncthreads();
        }
        #pragma unroll
        for (int a = 0; a < 2; ++a)
            #pragma unroll
            for (int i = 0; i < 4; ++i) {
                const int row = a * 64 + ty * 4 + i;
                if (row >= NL_) continue;
                #pragma unroll
                for (int j = 0; j < 4; ++j) {
                    const long col = n0 + tx * 4 + j;
                    qf[(long)row * H_ + col] = 0.125f * (acc[a][i][j] + ipb[col]);
                }
            }
        return;
    }

    // ---- M2 tile: 4 labels x 64 cols, coalesced ow reads, unroll 8 ----
    {
        const int b3 = b - PB_CONV - PB_QF;
        const int jg = b3 % 12, lg = b3 / 12;
        const int tx = tid & 63, ty = tid >> 6;
        const int hcol = jg * 64 + tx;
        const int l = lg * 4 + ty;
        if (l >= NL_) return;
        float acc = 0.f;
        #pragma unroll 8
        for (int j = 0; j < H_; ++j)
            acc += lwt[(long)l * H_ + j] * ow[(long)j * H_ + hcol];
        M2[(long)l * H_ + hcol] = acc;
    }
}

// ---------------------------------------------------------------------------
// prep2: blocks 0..287: qk[(h*50+l), j] = sum_d qf[l,h64+d]*wk[h64+d, j]
//                       W2[(h*50+l), j] = sum_d M2[l,h64+d]*wv[h64+d, j]
//        (bk dropped: per-column constant cancels in softmax over s)
//        block 288: zero pad rows 600..639 of both
//        block 289: constL[l] = sum_i M2[l,i]*bv[i] + lw[l,i]*ob[i]
// ---------------------------------------------------------------------------
__global__ __launch_bounds__(256)
void prep2(const float* __restrict__ qf, const float* __restrict__ M2,
           const float* __restrict__ ipw, const float* __restrict__ ipb,
           const float* __restrict__ lwt, const float* __restrict__ ob,
           u16* __restrict__ qkL, u16* __restrict__ W2L, float* __restrict__ constL)
{
    const int b = blockIdx.x, t = threadIdx.x;
    if (b < 288) {
        const int mat = b / 144, r2 = b % 144, h = r2 / 12, jg = r2 % 12;
        const int tx = t & 63, ty = t >> 6;      // 64 cols x 4 row-groups(13)
        const int j = jg * 64 + tx;
        const int l0 = ty * 13;
        const float* A = (mat == 0 ? qf : M2);
        const float* B = ipw + ((long)(H_ + mat * H_ + h * DH_)) * H_ + j;
        u16* O = (mat == 0 ? qkL : W2L);
        float acc[13];
        #pragma unroll
        for (int r = 0; r < 13; ++r) acc[r] = 0.f;
        #pragma unroll 4
        for (int d = 0; d < DH_; ++d) {
            const float bv = B[(long)d * H_];
            #pragma unroll
            for (int r = 0; r < 13; ++r)
                if (l0 + r < NL_) acc[r] += A[(long)(l0 + r) * H_ + h * DH_ + d] * bv;
        }
        #pragma unroll
        for (int r = 0; r < 13; ++r)
            if (l0 + r < NL_)
                O[(long)(h * NL_ + l0 + r) * H_ + j] = f2b(acc[r]);
        return;
    }
    if (b == 288) {
        for (int i = t; i < 40 * H_; i += 256) {
            qkL[(long)600 * H_ + i] = 0;
            W2L[(long)600 * H_ + i] = 0;
        }
        return;
    }
    // b == 289: constL
    __shared__ float r4[4];
    const int lane = t & 63, w = t >> 6;
    for (int l = 0; l < NL_; ++l) {
        float s = 0.f;
        for (int i = t; i < H_; i += 256)
            s += M2[(long)l * H_ + i] * ipb[2 * H_ + i] + lwt[(long)l * H_ + i] * ob[i];
        #pragma unroll
        for (int o2 = 1; o2 < 64; o2 <<= 1) s += __shfl_xor(s, o2);
        if (lane == 0) r4[w] = s;
        __syncthreads();
        if (t == 0) constL[l] = r4[0] + r4[1] + r4[2] + r4[3];
        __syncthreads();
    }
}

// ---------------------------------------------------------------------------
// fused_gemm: block = (128 s-rows) x (64 lh-cols), computes BOTH
//   logits = enc @ qk^T  and  Z = enc @ W2^T  for the tile, then the
//   softmax PARTIALS over its 128 rows in the epilogue.
// K-loop: 3-buffer rotation + counted vmcnt(4) + raw s_barrier.
// ---------------------------------------------------------------------------
__global__ __launch_bounds__(256)
void fused_gemm(const u16* __restrict__ enc_b, const u16* __restrict__ qkL,
                const u16* __restrict__ W2L,
                float* __restrict__ pmg, float* __restrict__ ppg,
                float* __restrict__ pzg)
{
    const int flat = blockIdx.y * NT3_ + blockIdx.x;       // 0..639
    const int rem  = (flat & 7) * 80 + (flat >> 3);        // XCD-bijective
    const int mt   = rem / NT3_, ntb = rem % NT3_;
    const long m0 = (long)mt * 128, n0 = (long)ntb * 64;

    __shared__ u16 As[3][4096];      // 128 x 32
    __shared__ u16 Bqs[3][2048];     // 64 x 32
    __shared__ u16 Bzs[3][2048];
    __shared__ float redm[128], redsum[128], redz[128];

    const int tid = threadIdx.x, lane = tid & 63, w = tid >> 6;
    const int wr = w >> 1, wc = w & 1;
    const int sr0 = tid >> 2, sp = tid & 3;

    f32x4 accq[4][2], accz[4][2];
    #pragma unroll
    for (int m = 0; m < 4; ++m)
        #pragma unroll
        for (int n = 0; n < 2; ++n)
            #pragma unroll
            for (int j = 0; j < 4; ++j) { accq[m][n][j] = 0.f; accz[m][n][j] = 0.f; }

    auto stage = [&](int t, int buf) {
        const int k0 = t * 32;
        #pragma unroll
        for (int tt = 0; tt < 2; ++tt) {
            const int row = tt * 64 + sr0;
            const int ss  = sp ^ ((row >> 1) & 3);
            __builtin_amdgcn_global_load_lds(AS1(enc_b + (m0 + row) * H_ + k0 + ss * 8),
                                             AS3(As[buf] + (tt * 256 + tid) * 8), 16, 0, 0);
        }
        const int ss0 = sp ^ ((sr0 >> 1) & 3);
        __builtin_amdgcn_global_load_lds(AS1(qkL + (n0 + sr0) * H_ + k0 + ss0 * 8),
                                         AS3(Bqs[buf] + tid * 8), 16, 0, 0);
        __builtin_amdgcn_global_load_lds(AS1(W2L + (n0 + sr0) * H_ + k0 + ss0 * 8),
                                         AS3(Bzs[buf] + tid * 8), 16, 0, 0);
    };

    stage(0, 0);
    stage(1, 1);

    const int rr = lane & 15, g = lane >> 4;
    const int ro = (g ^ ((rr >> 1) & 3)) * 8;

    for (int t = 0; t < 24; ++t) {
        if (t < 23) asm volatile("s_waitcnt vmcnt(4)" ::: "memory");
        else        asm volatile("s_waitcnt vmcnt(0)" ::: "memory");
        __builtin_amdgcn_s_barrier();
        __builtin_amdgcn_sched_barrier(0);

        const int cb = t % 3;
        short8 a[4], bq[2], bz[2];
        #pragma unroll
        for (int m = 0; m < 4; ++m)
            a[m] = *reinterpret_cast<const short8*>(As[cb] + (wr * 64 + m * 16 + rr) * 32 + ro);
        #pragma unroll
        for (int n = 0; n < 2; ++n) {
            bq[n] = *reinterpret_cast<const short8*>(Bqs[cb] + (wc * 32 + n * 16 + rr) * 32 + ro);
            bz[n] = *reinterpret_cast<const short8*>(Bzs[cb] + (wc * 32 + n * 16 + rr) * 32 + ro);
        }
        #pragma unroll
        for (int m = 0; m < 4; ++m)
            #pragma unroll
            for (int n = 0; n < 2; ++n) {
                accq[m][n] = __builtin_amdgcn_mfma_f32_16x16x32_bf16(a[m], bq[n], accq[m][n], 0, 0, 0);
                accz[m][n] = __builtin_amdgcn_mfma_f32_16x16x32_bf16(a[m], bz[n], accz[m][n], 0, 0, 0);
            }

        if (t + 2 < 24) stage(t + 2, (t + 2) % 3);
    }

    // ---- epilogue: softmax partials over this block's 128 rows ----
    // acc element (m,n,j): row = wr*64 + m*16 + g*4 + j, col = wc*32 + n*16 + rr
    #pragma unroll
    for (int n = 0; n < 2; ++n) {
        float m_ = -INFINITY;
        #pragma unroll
        for (int mm = 0; mm < 4; ++mm)
            #pragma unroll
            for (int j = 0; j < 4; ++j) m_ = fmaxf(m_, accq[mm][n][j]);
        m_ = fmaxf(m_, __shfl_xor(m_, 16));
        m_ = fmaxf(m_, __shfl_xor(m_, 32));
        if (g == 0) redm[wr * 64 + wc * 32 + n * 16 + rr] = m_;
    }
    __syncthreads();
    #pragma unroll
    for (int n = 0; n < 2; ++n) {
        const int col = wc * 32 + n * 16 + rr;
        const float gm = fmaxf(redm[col], redm[64 + col]);
        float s_ = 0.f, z_ = 0.f;
        #pragma unroll
        for (int mm = 0; mm < 4; ++mm)
            #pragma unroll
            for (int j = 0; j < 4; ++j) {
                const float e = __expf(accq[mm][n][j] - gm);
                s_ += e;
                z_ += e * accz[mm][n][j];
            }
        s_ += __shfl_xor(s_, 16); s_ += __shfl_xor(s_, 32);
        z_ += __shfl_xor(z_, 16); z_ += __shfl_xor(z_, 32);
        if (g == 0) { redsum[wr * 64 + col] = s_; redz[wr * 64 + col] = z_; }
    }
    __syncthreads();
    if (tid < 64) {
        const int col = tid;
        const long o = (long)mt * NLH_ + n0 + col;
        pmg[o] = fmaxf(redm[col], redm[64 + col]);
        ppg[o] = redsum[col] + redsum[64 + col];
        pzg[o] = redz[col] + redz[64 + col];
    }
}

// ---------------------------------------------------------------------------
// combine: block = label l, 64 threads. Thread h (<12) runs the 64-step
// scalar flash-prefix over m-tiles; emits at every 4th tile (512-row chunk).
// ---------------------------------------------------------------------------
__global__ __launch_bounds__(64)
void combine(const float* __restrict__ pmg, const float* __restrict__ ppg,
             const float* __restrict__ pzg, const float* __restrict__ constL,
             float* __restrict__ out)
{
    const int l = blockIdx.x, t = threadIdx.x;
    __shared__ float sc[16][12];
    if (t < NH_) {
        const int lh = t * NL_ + l;
        float M = -INFINITY, S = 0.f, A = 0.f;
        for (int mt = 0; mt < MT_; ++mt) {
            const long o = (long)mt * NLH_ + lh;
            const float mc = pmg[o], pc = ppg[o], zc = pzg[o];
            const float Mn = fmaxf(M, mc);
            const float ea = __expf(M - Mn), eb = __expf(mc - Mn);
            S = S * ea + pc * eb;
            A = A * ea + zc * eb;
            M = Mn;
            if ((mt & 3) == 3) sc[mt >> 2][t] = A / S;
        }
    }
    __syncthreads();
    if (t < NC_) {
        float s = constL[l];
        #pragma unroll
        for (int h = 0; h < NH_; ++h) s += sc[t][h];
        out[(long)t * NL_ + l] = s;
    }
}

// ---------------------------------------------------------------------------
extern "C" void kernel_launch(void* const* d_in, const int* in_sizes, int n_in,
                              void* d_out, int out_size, void* d_ws, size_t ws_size,
                              hipStream_t stream) {
    const float* enc = (const float*)d_in[0];
    const float* lq  = (const float*)d_in[1];
    const float* lwt = (const float*)d_in[2];   // flat == lw (50, 768)
    const float* ipw = (const float*)d_in[3];
    const float* ipb = (const float*)d_in[4];
    const float* ow  = (const float*)d_in[5];
    const float* ob  = (const float*)d_in[6];
    float* out = (float*)d_out;

    // workspace
    float* wsf    = (float*)d_ws;
    float* qf     = wsf;                         // 50*768
    float* M2     = qf + (long)NL_ * H_;         // 50*768
    float* constL = M2 + (long)NL_ * H_;         // 64
    float* pmg    = constL + 64;                 // 64*640
    float* ppg    = pmg + (long)MT_ * NLH_;
    float* pzg    = ppg + (long)MT_ * NLH_;
    u16* enc_b = (u16*)(pzg + (long)MT_ * NLH_); // 8192*768
    u16* qkL   = enc_b + (long)S_ * H_;          // 640*768
    u16* W2L   = qkL + (long)NLH_ * H_;          // 640*768

    prep1<<<dim3(PB_CONV + PB_QF + PB_M2), 256, 0, stream>>>(
        enc, lq, lwt, ipw, ipb, ow, enc_b, qf, M2);

    prep2<<<dim3(290), 256, 0, stream>>>(qf, M2, ipw, ipb, lwt, ob,
                                         qkL, W2L, constL);

    fused_gemm<<<dim3(NT3_, MT_), 256, 0, stream>>>(enc_b, qkL, W2L, pmg, ppg, pzg);

    combine<<<dim3(NL_), 64, 0, stream>>>(pmg, ppg, pzg, constL, out);
}

// Round 9
// 82.172 us; speedup vs baseline: 7.7871x; 2.2657x over previous
//
#include <hip/hip_runtime.h>
#include <math.h>

// Problem constants
#define H_   768
#define NH_  12
#define DH_  64
#define NL_  50
#define NC_  16
#define S_   8192
#define NLH_ 640     // padded (h,l) columns (600 used)
#define MT_  64      // m-tiles of 128 s-rows
#define NT3_ 10      // n-tiles of 64 cols

typedef __attribute__((ext_vector_type(8))) short short8;
typedef __attribute__((ext_vector_type(4))) short short4v;
typedef __attribute__((ext_vector_type(4))) float f32x4;
typedef unsigned short u16;

#define AS1(p) ((const __attribute__((address_space(1))) void*)(p))
#define AS3(p) ((__attribute__((address_space(3))) void*)(p))

__device__ inline u16 f2b(float f) {
    union { float f; unsigned u; } x; x.f = f;
    return (u16)((x.u + 0x7FFFu + ((x.u >> 16) & 1u)) >> 16);
}
__device__ inline short8 cvt8(const float* __restrict__ src) {
    const float4 v0 = *reinterpret_cast<const float4*>(src);
    const float4 v1 = *reinterpret_cast<const float4*>(src + 4);
    short8 o;
    o[0] = f2b(v0.x); o[1] = f2b(v0.y); o[2] = f2b(v0.z); o[3] = f2b(v0.w);
    o[4] = f2b(v1.x); o[5] = f2b(v1.y); o[6] = f2b(v1.z); o[7] = f2b(v1.w);
    return o;
}

// ---------------------------------------------------------------------------
// prep1 (one launch):
//   blocks 0..3071 : enc fp32 -> bf16 (linear, BW-bound)
//   blocks 3072..3077 : qf = 0.125*(lq @ wq^T + bq)   MFMA 64x128 tile, K=768
//   blocks 3078..3083 : M2 = lw @ ow                  MFMA, B LDS-transposed
// ---------------------------------------------------------------------------
#define PB_CONV 3072

__global__ __launch_bounds__(256)
void prep1(const float* __restrict__ enc, const float* __restrict__ lq,
           const float* __restrict__ lwt, const float* __restrict__ ipw,
           const float* __restrict__ ipb, const float* __restrict__ ow,
           u16* __restrict__ enc_b, float* __restrict__ qf, float* __restrict__ M2)
{
    __shared__ u16 As[64 * 32];    // 4 KB
    __shared__ u16 Bs[128 * 32];   // 8 KB

    const int b = blockIdx.x, tid = threadIdx.x;

    if (b < PB_CONV) {
        const long i8 = (long)b * 2048 + (long)tid * 8;
        *reinterpret_cast<short8*>(enc_b + i8) = cvt8(enc + i8);
        return;
    }

    const bool isM2 = (b >= PB_CONV + 6);
    const long n0 = (long)(b - PB_CONV - (isM2 ? 6 : 0)) * 128;
    const int lane = tid & 63, w = tid >> 6;
    const int rr = lane & 15, g = lane >> 4;

    f32x4 acc[4][2];
    #pragma unroll
    for (int m = 0; m < 4; ++m)
        #pragma unroll
        for (int n = 0; n < 2; ++n)
            #pragma unroll
            for (int j = 0; j < 4; ++j) acc[m][n][j] = 0.f;

    const float* Asrc = isM2 ? lwt : lq;

    for (int k0 = 0; k0 < H_; k0 += 32) {
        // A stage: 64 rows x 32 k (rows >= 50 zero)
        {
            const int row = tid >> 2, sp = tid & 3;
            short8 o;
            #pragma unroll
            for (int i = 0; i < 8; ++i) o[i] = 0;
            if (row < NL_) o = cvt8(Asrc + (long)row * H_ + k0 + sp * 8);
            const int ss = sp ^ ((row >> 1) & 3);
            *reinterpret_cast<short8*>(As + row * 32 + ss * 8) = o;
        }
        if (!isM2) {
            // B = wq rows (NT): 128 rows x 32 k, coalesced
            #pragma unroll
            for (int it = 0; it < 2; ++it) {
                const int gid = it * 256 + tid;
                const int row = gid >> 2, sp = gid & 3;
                const short8 o = cvt8(ipw + (n0 + row) * H_ + k0 + sp * 8);
                const int ss = sp ^ ((row >> 1) & 3);
                *reinterpret_cast<short8*>(Bs + row * 32 + ss * 8) = o;
            }
        } else {
            // B = ow (NN): transpose-stage 32 k-rows x 128 n
            #pragma unroll
            for (int it = 0; it < 4; ++it) {
                const int gid = it * 256 + tid;       // kq*128 + n
                const int n = gid & 127, kq = gid >> 7;
                short4v o4;
                #pragma unroll
                for (int i = 0; i < 4; ++i)
                    o4[i] = f2b(ow[(long)(k0 + kq * 4 + i) * H_ + n0 + n]);
                const int byte = n * 64 + (((kq >> 1) ^ ((n >> 1) & 3)) << 4) + (kq & 1) * 8;
                *reinterpret_cast<short4v*>((char*)Bs + byte) = o4;
            }
        }
        __syncthreads();

        short8 a[4], bb[2];
        #pragma unroll
        for (int m = 0; m < 4; ++m) {
            const int row = m * 16 + rr;
            a[m] = *reinterpret_cast<const short8*>(As + row * 32 + ((g ^ ((row >> 1) & 3)) * 8));
        }
        #pragma unroll
        for (int n = 0; n < 2; ++n) {
            const int nr = w * 32 + n * 16 + rr;
            bb[n] = *reinterpret_cast<const short8*>(Bs + nr * 32 + ((g ^ ((nr >> 1) & 3)) * 8));
        }
        #pragma unroll
        for (int m = 0; m < 4; ++m)
            #pragma unroll
            for (int n = 0; n < 2; ++n)
                acc[m][n] = __builtin_amdgcn_mfma_f32_16x16x32_bf16(a[m], bb[n], acc[m][n], 0, 0, 0);
        __syncthreads();
    }

    float* O = isM2 ? M2 : qf;
    #pragma unroll
    for (int m = 0; m < 4; ++m)
        #pragma unroll
        for (int n = 0; n < 2; ++n) {
            const long col = n0 + w * 32 + n * 16 + rr;
            #pragma unroll
            for (int j = 0; j < 4; ++j) {
                const int row = m * 16 + g * 4 + j;
                if (row < NL_) {
                    float v = acc[m][n][j];
                    if (!isM2) v = 0.125f * (v + ipb[col]);
                    O[(long)row * H_ + col] = v;
                }
            }
        }
}

// ---------------------------------------------------------------------------
// prep2 (one launch):
//   blocks 0..143 : (mat, h, jt): qk/W2 = A_h @ wk_h/wv_h   MFMA, K=64 one-shot
//   blocks 144..193 : constL[l]
//   block 194 : zero pad rows 600..639 of qkL, W2L
// ---------------------------------------------------------------------------
__global__ __launch_bounds__(256)
void prep2(const float* __restrict__ qf, const float* __restrict__ M2,
           const float* __restrict__ ipw, const float* __restrict__ ipb,
           const float* __restrict__ lwt, const float* __restrict__ ob,
           u16* __restrict__ qkL, u16* __restrict__ W2L, float* __restrict__ constL)
{
    __shared__ u16 As2[64 * 64];    // 8 KB
    __shared__ u16 Bs2[128 * 64];   // 16 KB

    const int b = blockIdx.x, tid = threadIdx.x;

    if (b < 144) {
        const int mat = b / 72, r2 = b % 72, h = r2 / 6, jt = r2 % 6;
        const long n0 = (long)jt * 128;
        const int kb = H_ + mat * H_ + h * DH_;      // ipw row base (wk / wv)
        const float* Asrc = mat ? M2 : qf;
        const int lane = tid & 63, w = tid >> 6;
        const int rr = lane & 15, g = lane >> 4;

        // A stage: 64 rows x 64 k from Asrc[row][h*64 + k]
        #pragma unroll
        for (int it = 0; it < 2; ++it) {
            const int gid = it * 256 + tid;          // row*8 + sp
            const int row = gid >> 3, sp = gid & 7;
            short8 o;
            #pragma unroll
            for (int i = 0; i < 8; ++i) o[i] = 0;
            if (row < NL_) o = cvt8(Asrc + (long)row * H_ + h * DH_ + sp * 8);
            *reinterpret_cast<short8*>(As2 + row * 64 + ((sp ^ (row & 7)) * 8)) = o;
        }
        // B stage: transpose 64 k-rows x 128 n from ipw[kb+k][n0+n]
        #pragma unroll
        for (int it = 0; it < 8; ++it) {
            const int gid = it * 256 + tid;          // kq*128 + n, kq 0..15
            const int n = gid & 127, kq = gid >> 7;
            short4v o4;
            #pragma unroll
            for (int i = 0; i < 4; ++i)
                o4[i] = f2b(ipw[(long)(kb + kq * 4 + i) * H_ + n0 + n]);
            const int byte = n * 128 + (((kq >> 1) ^ (n & 7)) << 4) + (kq & 1) * 8;
            *reinterpret_cast<short4v*>((char*)Bs2 + byte) = o4;
        }
        __syncthreads();

        f32x4 acc[4][2];
        #pragma unroll
        for (int m = 0; m < 4; ++m)
            #pragma unroll
            for (int n = 0; n < 2; ++n)
                #pragma unroll
                for (int j = 0; j < 4; ++j) acc[m][n][j] = 0.f;

        #pragma unroll
        for (int ks = 0; ks < 2; ++ks) {
            short8 a[4], bb[2];
            #pragma unroll
            for (int m = 0; m < 4; ++m) {
                const int row = m * 16 + rr, s = ks * 4 + g;
                a[m] = *reinterpret_cast<const short8*>(As2 + row * 64 + ((s ^ (row & 7)) * 8));
            }
            #pragma unroll
            for (int n = 0; n < 2; ++n) {
                const int nr = w * 32 + n * 16 + rr, s = ks * 4 + g;
                bb[n] = *reinterpret_cast<const short8*>(Bs2 + nr * 64 + ((s ^ (nr & 7)) * 8));
            }
            #pragma unroll
            for (int m = 0; m < 4; ++m)
                #pragma unroll
                for (int n = 0; n < 2; ++n)
                    acc[m][n] = __builtin_amdgcn_mfma_f32_16x16x32_bf16(a[m], bb[n], acc[m][n], 0, 0, 0);
        }

        u16* O = mat ? W2L : qkL;
        #pragma unroll
        for (int m = 0; m < 4; ++m)
            #pragma unroll
            for (int n = 0; n < 2; ++n) {
                const long col = n0 + w * 32 + n * 16 + rr;
                #pragma unroll
                for (int j = 0; j < 4; ++j) {
                    const int l = m * 16 + g * 4 + j;
                    if (l < NL_)
                        O[(long)(h * NL_ + l) * H_ + col] = f2b(acc[m][n][j]);
                }
            }
        return;
    }

    if (b < 194) {   // constL[l]
        const int l = b - 144;
        __shared__ float r4[4];
        const int lane = tid & 63, w = tid >> 6;
        float s = 0.f;
        #pragma unroll
        for (int r = 0; r < 3; ++r) {
            const int i = tid + 256 * r;
            s += M2[(long)l * H_ + i] * ipb[2 * H_ + i] + lwt[(long)l * H_ + i] * ob[i];
        }
        #pragma unroll
        for (int o2 = 1; o2 < 64; o2 <<= 1) s += __shfl_xor(s, o2);
        if (lane == 0) r4[w] = s;
        __syncthreads();
        if (tid == 0) constL[l] = r4[0] + r4[1] + r4[2] + r4[3];
        return;
    }

    // b == 194: zero pad rows 600..639
    {
        short8 z;
        #pragma unroll
        for (int i = 0; i < 8; ++i) z[i] = 0;
        for (int i = tid; i < 40 * H_ / 8; i += 256) {
            *reinterpret_cast<short8*>(qkL + (long)600 * H_ + i * 8) = z;
            *reinterpret_cast<short8*>(W2L + (long)600 * H_ + i * 8) = z;
        }
    }
}

// ---------------------------------------------------------------------------
// fused_gemm: block = (128 s-rows) x (64 lh-cols), computes BOTH
//   logits = enc @ qk^T  and  Z = enc @ W2^T, then softmax partials over
//   its 128 rows. K-loop: 3-buffer rotation + counted vmcnt(4) + s_barrier.
// ---------------------------------------------------------------------------
__global__ __launch_bounds__(256)
void fused_gemm(const u16* __restrict__ enc_b, const u16* __restrict__ qkL,
                const u16* __restrict__ W2L,
                float* __restrict__ pmg, float* __restrict__ ppg,
                float* __restrict__ pzg)
{
    const int flat = blockIdx.y * NT3_ + blockIdx.x;       // 0..639
    const int rem  = (flat & 7) * 80 + (flat >> 3);        // XCD-bijective
    const int mt   = rem / NT3_, ntb = rem % NT3_;
    const long m0 = (long)mt * 128, n0 = (long)ntb * 64;

    __shared__ u16 As[3][4096];      // 128 x 32
    __shared__ u16 Bqs[3][2048];     // 64 x 32
    __shared__ u16 Bzs[3][2048];
    __shared__ float redm[128], redsum[128], redz[128];

    const int tid = threadIdx.x, lane = tid & 63, w = tid >> 6;
    const int wr = w >> 1, wc = w & 1;
    const int sr0 = tid >> 2, sp = tid & 3;

    f32x4 accq[4][2], accz[4][2];
    #pragma unroll
    for (int m = 0; m < 4; ++m)
        #pragma unroll
        for (int n = 0; n < 2; ++n)
            #pragma unroll
            for (int j = 0; j < 4; ++j) { accq[m][n][j] = 0.f; accz[m][n][j] = 0.f; }

    auto stage = [&](int t, int buf) {
        const int k0 = t * 32;
        #pragma unroll
        for (int tt = 0; tt < 2; ++tt) {
            const int row = tt * 64 + sr0;
            const int ss  = sp ^ ((row >> 1) & 3);
            __builtin_amdgcn_global_load_lds(AS1(enc_b + (m0 + row) * H_ + k0 + ss * 8),
                                             AS3(As[buf] + (tt * 256 + tid) * 8), 16, 0, 0);
        }
        const int ss0 = sp ^ ((sr0 >> 1) & 3);
        __builtin_amdgcn_global_load_lds(AS1(qkL + (n0 + sr0) * H_ + k0 + ss0 * 8),
                                         AS3(Bqs[buf] + tid * 8), 16, 0, 0);
        __builtin_amdgcn_global_load_lds(AS1(W2L + (n0 + sr0) * H_ + k0 + ss0 * 8),
                                         AS3(Bzs[buf] + tid * 8), 16, 0, 0);
    };

    stage(0, 0);
    stage(1, 1);

    const int rr = lane & 15, g = lane >> 4;
    const int ro = (g ^ ((rr >> 1) & 3)) * 8;

    for (int t = 0; t < 24; ++t) {
        if (t < 23) asm volatile("s_waitcnt vmcnt(4)" ::: "memory");
        else        asm volatile("s_waitcnt vmcnt(0)" ::: "memory");
        __builtin_amdgcn_s_barrier();
        __builtin_amdgcn_sched_barrier(0);

        const int cb = t % 3;
        short8 a[4], bq[2], bz[2];
        #pragma unroll
        for (int m = 0; m < 4; ++m)
            a[m] = *reinterpret_cast<const short8*>(As[cb] + (wr * 64 + m * 16 + rr) * 32 + ro);
        #pragma unroll
        for (int n = 0; n < 2; ++n) {
            bq[n] = *reinterpret_cast<const short8*>(Bqs[cb] + (wc * 32 + n * 16 + rr) * 32 + ro);
            bz[n] = *reinterpret_cast<const short8*>(Bzs[cb] + (wc * 32 + n * 16 + rr) * 32 + ro);
        }
        #pragma unroll
        for (int m = 0; m < 4; ++m)
            #pragma unroll
            for (int n = 0; n < 2; ++n) {
                accq[m][n] = __builtin_amdgcn_mfma_f32_16x16x32_bf16(a[m], bq[n], accq[m][n], 0, 0, 0);
                accz[m][n] = __builtin_amdgcn_mfma_f32_16x16x32_bf16(a[m], bz[n], accz[m][n], 0, 0, 0);
            }

        if (t + 2 < 24) stage(t + 2, (t + 2) % 3);
    }

    // ---- epilogue: softmax partials over this block's 128 rows ----
    #pragma unroll
    for (int n = 0; n < 2; ++n) {
        float m_ = -INFINITY;
        #pragma unroll
        for (int mm = 0; mm < 4; ++mm)
            #pragma unroll
            for (int j = 0; j < 4; ++j) m_ = fmaxf(m_, accq[mm][n][j]);
        m_ = fmaxf(m_, __shfl_xor(m_, 16));
        m_ = fmaxf(m_, __shfl_xor(m_, 32));
        if (g == 0) redm[wr * 64 + wc * 32 + n * 16 + rr] = m_;
    }
    __syncthreads();
    #pragma unroll
    for (int n = 0; n < 2; ++n) {
        const int col = wc * 32 + n * 16 + rr;
        const float gm = fmaxf(redm[col], redm[64 + col]);
        float s_ = 0.f, z_ = 0.f;
        #pragma unroll
        for (int mm = 0; mm < 4; ++mm)
            #pragma unroll
            for (int j = 0; j < 4; ++j) {
                const float e = __expf(accq[mm][n][j] - gm);
                s_ += e;
                z_ += e * accz[mm][n][j];
            }
        s_ += __shfl_xor(s_, 16); s_ += __shfl_xor(s_, 32);
        z_ += __shfl_xor(z_, 16); z_ += __shfl_xor(z_, 32);
        if (g == 0) { redsum[wr * 64 + col] = s_; redz[wr * 64 + col] = z_; }
    }
    __syncthreads();
    if (tid < 64) {
        const int col = tid;
        const long o = (long)mt * NLH_ + n0 + col;
        pmg[o] = fmaxf(redm[col], redm[64 + col]);
        ppg[o] = redsum[col] + redsum[64 + col];
        pzg[o] = redz[col] + redz[64 + col];
    }
}

// ---------------------------------------------------------------------------
// combine: block = label l, 64 threads. LDS-preload all partials (coalesced
// issue of 36 independent loads/thread), then 12 threads run the serial
// flash-prefix from LDS; emit at every 4th m-tile.
// ---------------------------------------------------------------------------
__global__ __launch_bounds__(64)
void combine(const float* __restrict__ pmg, const float* __restrict__ ppg,
             const float* __restrict__ pzg, const float* __restrict__ constL,
             float* __restrict__ out)
{
    const int l = blockIdx.x, t = threadIdx.x;
    __shared__ float sm[64][12], sp_[64][12], sz[64][12];
    __shared__ float sc[16][12];

    #pragma unroll
    for (int h = 0; h < NH_; ++h) {
        const long o = (long)t * NLH_ + h * NL_ + l;
        sm[t][h]  = pmg[o];
        sp_[t][h] = ppg[o];
        sz[t][h]  = pzg[o];
    }
    __syncthreads();

    if (t < NH_) {
        float M = -INFINITY, S = 0.f, A = 0.f;
        for (int mt = 0; mt < MT_; ++mt) {
            const float mc = sm[mt][t], pc = sp_[mt][t], zc = sz[mt][t];
            const float Mn = fmaxf(M, mc);
            const float ea = __expf(M - Mn), eb = __expf(mc - Mn);
            S = S * ea + pc * eb;
            A = A * ea + zc * eb;
            M = Mn;
            if ((mt & 3) == 3) sc[mt >> 2][t] = A / S;
        }
    }
    __syncthreads();
    if (t < NC_) {
        float s = constL[l];
        #pragma unroll
        for (int h = 0; h < NH_; ++h) s += sc[t][h];
        out[(long)t * NL_ + l] = s;
    }
}

// ---------------------------------------------------------------------------
extern "C" void kernel_launch(void* const* d_in, const int* in_sizes, int n_in,
                              void* d_out, int out_size, void* d_ws, size_t ws_size,
                              hipStream_t stream) {
    const float* enc = (const float*)d_in[0];
    const float* lq  = (const float*)d_in[1];
    const float* lwt = (const float*)d_in[2];   // flat == lw (50, 768)
    const float* ipw = (const float*)d_in[3];
    const float* ipb = (const float*)d_in[4];
    const float* ow  = (const float*)d_in[5];
    const float* ob  = (const float*)d_in[6];
    float* out = (float*)d_out;

    // workspace
    float* wsf    = (float*)d_ws;
    float* qf     = wsf;                         // 50*768
    float* M2     = qf + (long)NL_ * H_;         // 50*768
    float* constL = M2 + (long)NL_ * H_;         // 64
    float* pmg    = constL + 64;                 // 64*640
    float* ppg    = pmg + (long)MT_ * NLH_;
    float* pzg    = ppg + (long)MT_ * NLH_;
    u16* enc_b = (u16*)(pzg + (long)MT_ * NLH_); // 8192*768
    u16* qkL   = enc_b + (long)S_ * H_;          // 640*768
    u16* W2L   = qkL + (long)NLH_ * H_;          // 640*768

    prep1<<<dim3(PB_CONV + 12), 256, 0, stream>>>(
        enc, lq, lwt, ipw, ipb, ow, enc_b, qf, M2);

    prep2<<<dim3(195), 256, 0, stream>>>(qf, M2, ipw, ipb, lwt, ob,
                                         qkL, W2L, constL);

    fused_gemm<<<dim3(NT3_, MT_), 256, 0, stream>>>(enc_b, qkL, W2L, pmg, ppg, pzg);

    combine<<<dim3(NL_), 64, 0, stream>>>(pmg, ppg, pzg, constL, out);
}

// Round 10
// 58.579 us; speedup vs baseline: 10.9235x; 1.4028x over previous
//
#include <hip/hip_runtime.h>
#include <math.h>

// Problem constants
#define H_   768
#define NH_  12
#define DH_  64
#define NL_  50
#define NC_  16
#define S_   8192
#define NLH_ 640     // padded (h,l) columns (600 used)
#define MT_  64      // m-tiles of 128 s-rows
#define NT3_ 10      // n-tiles of 64 cols
#define KC_  8       // split-K chunks for prep1 tiles

typedef __attribute__((ext_vector_type(8))) short short8;
typedef __attribute__((ext_vector_type(4))) short short4v;
typedef __attribute__((ext_vector_type(4))) float f32x4;
typedef unsigned short u16;

#define AS1(p) ((const __attribute__((address_space(1))) void*)(p))
#define AS3(p) ((__attribute__((address_space(3))) void*)(p))

__device__ inline u16 f2b(float f) {
    union { float f; unsigned u; } x; x.f = f;
    return (u16)((x.u + 0x7FFFu + ((x.u >> 16) & 1u)) >> 16);
}
__device__ inline short8 cvt8(const float* __restrict__ src) {
    const float4 v0 = *reinterpret_cast<const float4*>(src);
    const float4 v1 = *reinterpret_cast<const float4*>(src + 4);
    short8 o;
    o[0] = f2b(v0.x); o[1] = f2b(v0.y); o[2] = f2b(v0.z); o[3] = f2b(v0.w);
    o[4] = f2b(v1.x); o[5] = f2b(v1.y); o[6] = f2b(v1.z); o[7] = f2b(v1.w);
    return o;
}

// ---------------------------------------------------------------------------
// prep1 (one launch):
//   blocks 0..95   : SPLIT-K MFMA partial tiles for qf (mat 0) / M2 (mat 1):
//                    (mat, kc, jt) -> 64x128 tile, K-chunk of 96 (3 steps),
//                    f32 partials into pbuf[(mat*8+kc)*64+row][col]
//   blocks 96..3167: enc fp32 -> bf16 (linear, BW-bound)
// ---------------------------------------------------------------------------
#define PB_TILE 96

__global__ __launch_bounds__(256)
void prep1(const float* __restrict__ enc, const float* __restrict__ lq,
           const float* __restrict__ lwt, const float* __restrict__ ipw,
           const float* __restrict__ ow,
           u16* __restrict__ enc_b, float* __restrict__ pbuf)
{
    __shared__ u16 As[64 * 32];    // 4 KB
    __shared__ u16 Bs[128 * 32];   // 8 KB

    const int b = blockIdx.x, tid = threadIdx.x;

    if (b >= PB_TILE) {
        const long i8 = (long)(b - PB_TILE) * 2048 + (long)tid * 8;
        *reinterpret_cast<short8*>(enc_b + i8) = cvt8(enc + i8);
        return;
    }

    const int mat = b / 48, r2 = b % 48, kc = r2 / 6, jt = r2 % 6;
    const long n0 = (long)jt * 128;
    const bool isM2 = (mat == 1);
    const int lane = tid & 63, w = tid >> 6;
    const int rr = lane & 15, g = lane >> 4;

    f32x4 acc[4][2];
    #pragma unroll
    for (int m = 0; m < 4; ++m)
        #pragma unroll
        for (int n = 0; n < 2; ++n)
            #pragma unroll
            for (int j = 0; j < 4; ++j) acc[m][n][j] = 0.f;

    const float* Asrc = isM2 ? lwt : lq;

    #pragma unroll
    for (int ki = 0; ki < 3; ++ki) {
        const int k0 = kc * 96 + ki * 32;
        // A stage: 64 rows x 32 k (rows >= 50 zero)
        {
            const int row = tid >> 2, sp = tid & 3;
            short8 o;
            #pragma unroll
            for (int i = 0; i < 8; ++i) o[i] = 0;
            if (row < NL_) o = cvt8(Asrc + (long)row * H_ + k0 + sp * 8);
            const int ss = sp ^ ((row >> 1) & 3);
            *reinterpret_cast<short8*>(As + row * 32 + ss * 8) = o;
        }
        if (!isM2) {
            // B = wq rows (NT): 128 rows x 32 k, coalesced
            #pragma unroll
            for (int it = 0; it < 2; ++it) {
                const int gid = it * 256 + tid;
                const int row = gid >> 2, sp = gid & 3;
                const short8 o = cvt8(ipw + (n0 + row) * H_ + k0 + sp * 8);
                const int ss = sp ^ ((row >> 1) & 3);
                *reinterpret_cast<short8*>(Bs + row * 32 + ss * 8) = o;
            }
        } else {
            // B = ow (NN): transpose-stage 32 k-rows x 128 n
            #pragma unroll
            for (int it = 0; it < 4; ++it) {
                const int gid = it * 256 + tid;       // kq*128 + n
                const int n = gid & 127, kq = gid >> 7;
                short4v o4;
                #pragma unroll
                for (int i = 0; i < 4; ++i)
                    o4[i] = f2b(ow[(long)(k0 + kq * 4 + i) * H_ + n0 + n]);
                const int byte = n * 64 + (((kq >> 1) ^ ((n >> 1) & 3)) << 4) + (kq & 1) * 8;
                *reinterpret_cast<short4v*>((char*)Bs + byte) = o4;
            }
        }
        __syncthreads();

        short8 a[4], bb[2];
        #pragma unroll
        for (int m = 0; m < 4; ++m) {
            const int row = m * 16 + rr;
            a[m] = *reinterpret_cast<const short8*>(As + row * 32 + ((g ^ ((row >> 1) & 3)) * 8));
        }
        #pragma unroll
        for (int n = 0; n < 2; ++n) {
            const int nr = w * 32 + n * 16 + rr;
            bb[n] = *reinterpret_cast<const short8*>(Bs + nr * 32 + ((g ^ ((nr >> 1) & 3)) * 8));
        }
        #pragma unroll
        for (int m = 0; m < 4; ++m)
            #pragma unroll
            for (int n = 0; n < 2; ++n)
                acc[m][n] = __builtin_amdgcn_mfma_f32_16x16x32_bf16(a[m], bb[n], acc[m][n], 0, 0, 0);
        __syncthreads();
    }

    // write f32 partials (all 64 rows; rows >= 50 are zero)
    float* P = pbuf + (long)(mat * KC_ + kc) * 64 * H_;
    #pragma unroll
    for (int m = 0; m < 4; ++m)
        #pragma unroll
        for (int n = 0; n < 2; ++n) {
            const long col = n0 + w * 32 + n * 16 + rr;
            #pragma unroll
            for (int j = 0; j < 4; ++j) {
                const int row = m * 16 + g * 4 + j;
                P[(long)row * H_ + col] = acc[m][n][j];
            }
        }
}

// ---------------------------------------------------------------------------
// prep2 (one launch):
//   blocks 0..143 : (mat, h, jt): qk/W2 = A_h @ wk_h/wv_h  MFMA, K=64 one-shot
//                   A_h summed from 8 split-K partials; qf gets 0.125*(.+bq)
//   blocks 144..193 : constL[l]  (M2 summed from partials)
//   block 194 : zero pad rows 600..639 of qkL, W2L
// ---------------------------------------------------------------------------
__global__ __launch_bounds__(256)
void prep2(const float* __restrict__ pbuf, const float* __restrict__ ipw,
           const float* __restrict__ ipb, const float* __restrict__ lwt,
           const float* __restrict__ ob,
           u16* __restrict__ qkL, u16* __restrict__ W2L, float* __restrict__ constL)
{
    __shared__ u16 As2[64 * 64];    // 8 KB
    __shared__ u16 Bs2[128 * 64];   // 16 KB

    const int b = blockIdx.x, tid = threadIdx.x;

    if (b < 144) {
        const int mat = b / 72, r2 = b % 72, h = r2 / 6, jt = r2 % 6;
        const long n0 = (long)jt * 128;
        const int kb = H_ + mat * H_ + h * DH_;      // ipw row base (wk / wv)
        const int lane = tid & 63, w = tid >> 6;
        const int rr = lane & 15, g = lane >> 4;

        // A stage: 64 rows x 64 k; sum 8 split-K partials, apply scale/bias
        #pragma unroll
        for (int it = 0; it < 2; ++it) {
            const int gid = it * 256 + tid;          // row*8 + sp
            const int row = gid >> 3, sp = gid & 7;
            float a8[8];
            #pragma unroll
            for (int i = 0; i < 8; ++i) a8[i] = 0.f;
            #pragma unroll
            for (int kc = 0; kc < KC_; ++kc) {
                const float* p = pbuf + ((long)(mat * KC_ + kc) * 64 + row) * H_
                               + h * DH_ + sp * 8;
                const float4 v0 = *reinterpret_cast<const float4*>(p);
                const float4 v1 = *reinterpret_cast<const float4*>(p + 4);
                a8[0] += v0.x; a8[1] += v0.y; a8[2] += v0.z; a8[3] += v0.w;
                a8[4] += v1.x; a8[5] += v1.y; a8[6] += v1.z; a8[7] += v1.w;
            }
            short8 o;
            if (mat == 0) {
                #pragma unroll
                for (int i = 0; i < 8; ++i)
                    o[i] = f2b((row < NL_) ? 0.125f * (a8[i] + ipb[h * DH_ + sp * 8 + i]) : 0.f);
            } else {
                #pragma unroll
                for (int i = 0; i < 8; ++i) o[i] = f2b(a8[i]);
            }
            *reinterpret_cast<short8*>(As2 + row * 64 + ((sp ^ (row & 7)) * 8)) = o;
        }
        // B stage: transpose 64 k-rows x 128 n from ipw[kb+k][n0+n]
        #pragma unroll
        for (int it = 0; it < 8; ++it) {
            const int gid = it * 256 + tid;          // kq*128 + n, kq 0..15
            const int n = gid & 127, kq = gid >> 7;
            short4v o4;
            #pragma unroll
            for (int i = 0; i < 4; ++i)
                o4[i] = f2b(ipw[(long)(kb + kq * 4 + i) * H_ + n0 + n]);
            const int byte = n * 128 + (((kq >> 1) ^ (n & 7)) << 4) + (kq & 1) * 8;
            *reinterpret_cast<short4v*>((char*)Bs2 + byte) = o4;
        }
        __syncthreads();

        f32x4 acc[4][2];
        #pragma unroll
        for (int m = 0; m < 4; ++m)
            #pragma unroll
            for (int n = 0; n < 2; ++n)
                #pragma unroll
                for (int j = 0; j < 4; ++j) acc[m][n][j] = 0.f;

        #pragma unroll
        for (int ks = 0; ks < 2; ++ks) {
            short8 a[4], bb[2];
            #pragma unroll
            for (int m = 0; m < 4; ++m) {
                const int row = m * 16 + rr, s = ks * 4 + g;
                a[m] = *reinterpret_cast<const short8*>(As2 + row * 64 + ((s ^ (row & 7)) * 8));
            }
            #pragma unroll
            for (int n = 0; n < 2; ++n) {
                const int nr = w * 32 + n * 16 + rr, s = ks * 4 + g;
                bb[n] = *reinterpret_cast<const short8*>(Bs2 + nr * 64 + ((s ^ (nr & 7)) * 8));
            }
            #pragma unroll
            for (int m = 0; m < 4; ++m)
                #pragma unroll
                for (int n = 0; n < 2; ++n)
                    acc[m][n] = __builtin_amdgcn_mfma_f32_16x16x32_bf16(a[m], bb[n], acc[m][n], 0, 0, 0);
        }

        u16* O = mat ? W2L : qkL;
        #pragma unroll
        for (int m = 0; m < 4; ++m)
            #pragma unroll
            for (int n = 0; n < 2; ++n) {
                const long col = n0 + w * 32 + n * 16 + rr;
                #pragma unroll
                for (int j = 0; j < 4; ++j) {
                    const int l = m * 16 + g * 4 + j;
                    if (l < NL_)
                        O[(long)(h * NL_ + l) * H_ + col] = f2b(acc[m][n][j]);
                }
            }
        return;
    }

    if (b < 194) {   // constL[l]: M2 row summed from partials
        const int l = b - 144;
        __shared__ float r4[4];
        const int lane = tid & 63, w = tid >> 6;
        float s = 0.f;
        #pragma unroll
        for (int r = 0; r < 3; ++r) {
            const int i = tid + 256 * r;
            float m2v = 0.f;
            #pragma unroll
            for (int kc = 0; kc < KC_; ++kc)
                m2v += pbuf[((long)(KC_ + kc) * 64 + l) * H_ + i];
            s += m2v * ipb[2 * H_ + i] + lwt[(long)l * H_ + i] * ob[i];
        }
        #pragma unroll
        for (int o2 = 1; o2 < 64; o2 <<= 1) s += __shfl_xor(s, o2);
        if (lane == 0) r4[w] = s;
        __syncthreads();
        if (tid == 0) constL[l] = r4[0] + r4[1] + r4[2] + r4[3];
        return;
    }

    // b == 194: zero pad rows 600..639
    {
        short8 z;
        #pragma unroll
        for (int i = 0; i < 8; ++i) z[i] = 0;
        for (int i = tid; i < 40 * H_ / 8; i += 256) {
            *reinterpret_cast<short8*>(qkL + (long)600 * H_ + i * 8) = z;
            *reinterpret_cast<short8*>(W2L + (long)600 * H_ + i * 8) = z;
        }
    }
}

// ---------------------------------------------------------------------------
// fused_gemm: block = (128 s-rows) x (64 lh-cols), computes BOTH
//   logits = enc @ qk^T  and  Z = enc @ W2^T, then softmax partials over
//   its 128 rows. K-loop: 3-buffer rotation + counted vmcnt(4) + s_barrier.
// ---------------------------------------------------------------------------
__global__ __launch_bounds__(256)
void fused_gemm(const u16* __restrict__ enc_b, const u16* __restrict__ qkL,
                const u16* __restrict__ W2L,
                float* __restrict__ pmg, float* __restrict__ ppg,
                float* __restrict__ pzg)
{
    const int flat = blockIdx.y * NT3_ + blockIdx.x;       // 0..639
    const int rem  = (flat & 7) * 80 + (flat >> 3);        // XCD-bijective
    const int mt   = rem / NT3_, ntb = rem % NT3_;
    const long m0 = (long)mt * 128, n0 = (long)ntb * 64;

    __shared__ u16 As[3][4096];      // 128 x 32
    __shared__ u16 Bqs[3][2048];     // 64 x 32
    __shared__ u16 Bzs[3][2048];
    __shared__ float redm[128], redsum[128], redz[128];

    const int tid = threadIdx.x, lane = tid & 63, w = tid >> 6;
    const int wr = w >> 1, wc = w & 1;
    const int sr0 = tid >> 2, sp = tid & 3;

    f32x4 accq[4][2], accz[4][2];
    #pragma unroll
    for (int m = 0; m < 4; ++m)
        #pragma unroll
        for (int n = 0; n < 2; ++n)
            #pragma unroll
            for (int j = 0; j < 4; ++j) { accq[m][n][j] = 0.f; accz[m][n][j] = 0.f; }

    auto stage = [&](int t, int buf) {
        const int k0 = t * 32;
        #pragma unroll
        for (int tt = 0; tt < 2; ++tt) {
            const int row = tt * 64 + sr0;
            const int ss  = sp ^ ((row >> 1) & 3);
            __builtin_amdgcn_global_load_lds(AS1(enc_b + (m0 + row) * H_ + k0 + ss * 8),
                                             AS3(As[buf] + (tt * 256 + tid) * 8), 16, 0, 0);
        }
        const int ss0 = sp ^ ((sr0 >> 1) & 3);
        __builtin_amdgcn_global_load_lds(AS1(qkL + (n0 + sr0) * H_ + k0 + ss0 * 8),
                                         AS3(Bqs[buf] + tid * 8), 16, 0, 0);
        __builtin_amdgcn_global_load_lds(AS1(W2L + (n0 + sr0) * H_ + k0 + ss0 * 8),
                                         AS3(Bzs[buf] + tid * 8), 16, 0, 0);
    };

    stage(0, 0);
    stage(1, 1);

    const int rr = lane & 15, g = lane >> 4;
    const int ro = (g ^ ((rr >> 1) & 3)) * 8;

    for (int t = 0; t < 24; ++t) {
        if (t < 23) asm volatile("s_waitcnt vmcnt(4)" ::: "memory");
        else        asm volatile("s_waitcnt vmcnt(0)" ::: "memory");
        __builtin_amdgcn_s_barrier();
        __builtin_amdgcn_sched_barrier(0);

        const int cb = t % 3;
        short8 a[4], bq[2], bz[2];
        #pragma unroll
        for (int m = 0; m < 4; ++m)
            a[m] = *reinterpret_cast<const short8*>(As[cb] + (wr * 64 + m * 16 + rr) * 32 + ro);
        #pragma unroll
        for (int n = 0; n < 2; ++n) {
            bq[n] = *reinterpret_cast<const short8*>(Bqs[cb] + (wc * 32 + n * 16 + rr) * 32 + ro);
            bz[n] = *reinterpret_cast<const short8*>(Bzs[cb] + (wc * 32 + n * 16 + rr) * 32 + ro);
        }
        #pragma unroll
        for (int m = 0; m < 4; ++m)
            #pragma unroll
            for (int n = 0; n < 2; ++n) {
                accq[m][n] = __builtin_amdgcn_mfma_f32_16x16x32_bf16(a[m], bq[n], accq[m][n], 0, 0, 0);
                accz[m][n] = __builtin_amdgcn_mfma_f32_16x16x32_bf16(a[m], bz[n], accz[m][n], 0, 0, 0);
            }

        if (t + 2 < 24) stage(t + 2, (t + 2) % 3);
    }

    // ---- epilogue: softmax partials over this block's 128 rows ----
    #pragma unroll
    for (int n = 0; n < 2; ++n) {
        float m_ = -INFINITY;
        #pragma unroll
        for (int mm = 0; mm < 4; ++mm)
            #pragma unroll
            for (int j = 0; j < 4; ++j) m_ = fmaxf(m_, accq[mm][n][j]);
        m_ = fmaxf(m_, __shfl_xor(m_, 16));
        m_ = fmaxf(m_, __shfl_xor(m_, 32));
        if (g == 0) redm[wr * 64 + wc * 32 + n * 16 + rr] = m_;
    }
    __syncthreads();
    #pragma unroll
    for (int n = 0; n < 2; ++n) {
        const int col = wc * 32 + n * 16 + rr;
        const float gm = fmaxf(redm[col], redm[64 + col]);
        float s_ = 0.f, z_ = 0.f;
        #pragma unroll
        for (int mm = 0; mm < 4; ++mm)
            #pragma unroll
            for (int j = 0; j < 4; ++j) {
                const float e = __expf(accq[mm][n][j] - gm);
                s_ += e;
                z_ += e * accz[mm][n][j];
            }
        s_ += __shfl_xor(s_, 16); s_ += __shfl_xor(s_, 32);
        z_ += __shfl_xor(z_, 16); z_ += __shfl_xor(z_, 32);
        if (g == 0) { redsum[wr * 64 + col] = s_; redz[wr * 64 + col] = z_; }
    }
    __syncthreads();
    if (tid < 64) {
        const int col = tid;
        const long o = (long)mt * NLH_ + n0 + col;
        pmg[o] = fmaxf(redm[col], redm[64 + col]);
        ppg[o] = redsum[col] + redsum[64 + col];
        pzg[o] = redz[col] + redz[64 + col];
    }
}

// ---------------------------------------------------------------------------
// combine: block = label l, 64 threads. LDS-preload all partials, then 12
// threads run the serial flash-prefix from LDS; emit at every 4th m-tile.
// ---------------------------------------------------------------------------
__global__ __launch_bounds__(64)
void combine(const float* __restrict__ pmg, const float* __restrict__ ppg,
             const float* __restrict__ pzg, const float* __restrict__ constL,
             float* __restrict__ out)
{
    const int l = blockIdx.x, t = threadIdx.x;
    __shared__ float sm[64][12], sp_[64][12], sz[64][12];
    __shared__ float sc[16][12];

    #pragma unroll
    for (int h = 0; h < NH_; ++h) {
        const long o = (long)t * NLH_ + h * NL_ + l;
        sm[t][h]  = pmg[o];
        sp_[t][h] = ppg[o];
        sz[t][h]  = pzg[o];
    }
    __syncthreads();

    if (t < NH_) {
        float M = -INFINITY, S = 0.f, A = 0.f;
        for (int mt = 0; mt < MT_; ++mt) {
            const float mc = sm[mt][t], pc = sp_[mt][t], zc = sz[mt][t];
            const float Mn = fmaxf(M, mc);
            const float ea = __expf(M - Mn), eb = __expf(mc - Mn);
            S = S * ea + pc * eb;
            A = A * ea + zc * eb;
            M = Mn;
            if ((mt & 3) == 3) sc[mt >> 2][t] = A / S;
        }
    }
    __syncthreads();
    if (t < NC_) {
        float s = constL[l];
        #pragma unroll
        for (int h = 0; h < NH_; ++h) s += sc[t][h];
        out[(long)t * NL_ + l] = s;
    }
}

// ---------------------------------------------------------------------------
extern "C" void kernel_launch(void* const* d_in, const int* in_sizes, int n_in,
                              void* d_out, int out_size, void* d_ws, size_t ws_size,
                              hipStream_t stream) {
    const float* enc = (const float*)d_in[0];
    const float* lq  = (const float*)d_in[1];
    const float* lwt = (const float*)d_in[2];   // flat == lw (50, 768)
    const float* ipw = (const float*)d_in[3];
    const float* ipb = (const float*)d_in[4];
    const float* ow  = (const float*)d_in[5];
    const float* ob  = (const float*)d_in[6];
    float* out = (float*)d_out;

    // workspace
    float* wsf    = (float*)d_ws;
    float* pbuf   = wsf;                          // 2*8*64*768 = 786432
    float* constL = pbuf + (long)2 * KC_ * 64 * H_;  // 64
    float* pmg    = constL + 64;                  // 64*640
    float* ppg    = pmg + (long)MT_ * NLH_;
    float* pzg    = ppg + (long)MT_ * NLH_;
    u16* enc_b = (u16*)(pzg + (long)MT_ * NLH_);  // 8192*768
    u16* qkL   = enc_b + (long)S_ * H_;           // 640*768
    u16* W2L   = qkL + (long)NLH_ * H_;           // 640*768

    prep1<<<dim3(PB_TILE + 3072), 256, 0, stream>>>(
        enc, lq, lwt, ipw, ow, enc_b, pbuf);

    prep2<<<dim3(195), 256, 0, stream>>>(pbuf, ipw, ipb, lwt, ob,
                                         qkL, W2L, constL);

    fused_gemm<<<dim3(NT3_, MT_), 256, 0, stream>>>(enc_b, qkL, W2L, pmg, ppg, pzg);

    combine<<<dim3(NL_), 64, 0, stream>>>(pmg, ppg, pzg, constL, out);
}